// Round 10
// baseline (174.379 us; speedup 1.0000x reference)
//
#include <hip/hip_runtime.h>
#include <math.h>

#define NN 768
#define DD 64
#define WPB 4                        // waves per block in k_main
#define TPW2 (NN / 16 / WPB / 2)     // dual-tile iterations per wave = 6
#define RSTRIDE 34                   // LDS r-bounce row stride in dwords (pad 2)
#define PREBLKS 18                   // k_prepack: frag/pack blocks before row blocks

typedef _Float16 half8 __attribute__((ext_vector_type(8)));
typedef float    f32x4 __attribute__((ext_vector_type(4)));
typedef __fp16   p2f   __attribute__((ext_vector_type(2)));

union FragU { uint4 u4; unsigned int u[4]; half8 h; };
union PkU   { unsigned int u; p2f p; };

__device__ __forceinline__ unsigned int pk2(float a, float b) {
    PkU t; t.p = __builtin_amdgcn_cvt_pkrtz(a, b); return t.u;
}
__device__ __forceinline__ float lane_bcast(float v, int src) {
    return __int_as_float(__builtin_amdgcn_readlane(__float_as_int(v), src));
}
__device__ __forceinline__ f32x4 mfma16(FragU a, FragU b, f32x4 c) {
    return __builtin_amdgcn_mfma_f32_16x16x32_f16(a.h, b.h, c, 0, 0, 0);
}

// ---------- Kernel 0: pack fragments / hf16 / moments (blk<18) + per-row pre (blk>=18)
__global__ __launch_bounds__(256) void k_prepack(
    const float* __restrict__ hs, const float* __restrict__ ng_w,
    const float* __restrict__ ng_b, const float* __restrict__ war_w,
    const float* __restrict__ war_b,
    const float* __restrict__ rel_w, const float* __restrict__ rel_b,
    const float* __restrict__ rel_lw, const float* __restrict__ rel_lb,
    float* __restrict__ sbase, float* __restrict__ warb, float* __restrict__ war3,
    unsigned int* __restrict__ hf16,
    unsigned int* __restrict__ afragS, unsigned int* __restrict__ afragR,
    float* __restrict__ mom)
{
    const int t = threadIdx.x, blk = blockIdx.x;
    const int lane = t & 63, q = t >> 6, g = lane >> 4, c16 = lane & 15;

    if (blk >= PREBLKS) {
        // per-row: sbase = h@W2 + ng_b ; warb = h@war[64:128] + war_b ; war3 = h@war[128:192]
        const int row = (blk - PREBLKS) * 4 + q;
        const float hv = hs[row * DD + lane];
        float a2 = ng_b[lane];
        #pragma unroll 8
        for (int k = 0; k < DD; ++k)
            a2 = fmaf(lane_bcast(hv, k), ng_w[(DD + k) * DD + lane], a2);
        sbase[row * DD + lane] = a2;
        float t2 = hv * war_w[DD + lane];
        float t3 = hv * war_w[2 * DD + lane];
        #pragma unroll
        for (int o = 32; o; o >>= 1) { t2 += __shfl_xor(t2, o); t3 += __shfl_xor(t3, o); }
        if (lane == 0) { warb[row] = t2 + war_b[0]; war3[row] = t3; }
        return;
    }

    // hf16 pack across blocks 0..17
    for (int idx = blk * 256 + t; idx < NN * 32; idx += PREBLKS * 256) {
        const int row = idx >> 5, c = idx & 31;
        hf16[idx] = pk2(hs[row * DD + 2 * c], hs[row * DD + 2 * c + 1]);
    }

    if (blk < 16) {
        // GEMM2 S A-fragments: A[m=dout][k], frag id = b*4+c
        const int b = blk >> 2, c = blk & 3;
        const int dout = 16 * b + c16;
        const int k0 = 32 * c + g * 8 + 2 * q;
        const int r0 = (k0 < 64) ? k0 : (k0 + 64);   // W1 rows 0..63 ; W3 rows 128..191
        afragS[(blk * 64 + lane) * 4 + q] =
            pk2(ng_w[r0 * DD + dout], ng_w[(r0 + 1) * DD + dout]);
    } else if (blk == 16) {
        // GEMM1 A-fragments, split-precision:
        //   k0..5: wh (pairs xh) ; k8..13: wh (pairs xl) ; k16..21: wl (pairs xh)
        const int b = q;                      // m-block
        const int d = 16 * b + c16;
        const float rlwd = rel_lw[d], rlbd = rel_lb[d];
        const float c0 = rel_w[d] * rlwd;
        const float c1 = rel_w[DD + d] * rlwd;
        const float c2 = rel_w[2 * DD + d] * rlwd;
        const float c3 = rel_b[d] * rlwd;
        PkU h01, h23, h45;
        h01.p = __builtin_amdgcn_cvt_pkrtz(c0, c1);
        h23.p = __builtin_amdgcn_cvt_pkrtz(c2, c3);
        h45.p = __builtin_amdgcn_cvt_pkrtz(rlwd, rlbd);
        const unsigned l01 = pk2(c0 - (float)h01.p[0], c1 - (float)h01.p[1]);
        const unsigned l23 = pk2(c2 - (float)h23.p[0], c3 - (float)h23.p[1]);
        const unsigned l45 = pk2(rlwd - (float)h45.p[0], rlbd - (float)h45.p[1]);
        const unsigned int base = (b * 64 + lane) * 4;
        unsigned v0, v1, v2;
        if (g == 0 || g == 1)      { v0 = h01.u; v1 = h23.u; v2 = h45.u; }
        else if (g == 2)           { v0 = l01;   v1 = l23;   v2 = l45;   }
        else                       { v0 = 0u;    v1 = 0u;    v2 = 0u;    }
        afragR[base + 0] = v0;
        afragR[base + 1] = v1;
        afragR[base + 2] = v2;
        afragR[base + 3] = 0u;
    } else { // blk == 17: rel-LN moment matrix
        if (t < 64) {
            const float x0 = rel_w[t], x1 = rel_w[DD + t], x2 = rel_w[2 * DD + t];
            const float x3 = rel_b[t];
            float v[14] = {x0, x1, x2, x3,
                           x0 * x0, x1 * x1, x2 * x2, x3 * x3,
                           x0 * x1, x0 * x2, x0 * x3, x1 * x2, x1 * x3, x2 * x3};
            #pragma unroll
            for (int qq = 0; qq < 14; ++qq) {
                float s = v[qq];
                #pragma unroll
                for (int o = 32; o; o >>= 1) s += __shfl_xor(s, o);
                if (t == 0) mom[qq] = s * (1.f / 64.f);
            }
        }
    }
}

// ---------- Kernel 1: per-row i, dual 16-j tiles per iter via MFMA,
//            merged online softmax, fused final MLP + residual ---------------
__global__ __launch_bounds__(64 * WPB) void k_main(
    const float* __restrict__ corr, const int* __restrict__ nei,
    const float* __restrict__ hs, const float* __restrict__ av,
    const float* __restrict__ ng_lw, const float* __restrict__ ng_lb,
    const float* __restrict__ war_w,
    const float* __restrict__ sbase, const float* __restrict__ warb,
    const float* __restrict__ war3,
    const unsigned int* __restrict__ afragS, const unsigned int* __restrict__ afragR,
    const unsigned int* __restrict__ hf16, const float* __restrict__ mom,
    const float* __restrict__ wt_w, const float* __restrict__ wt_b,
    const float* __restrict__ wt_lw, const float* __restrict__ wt_lb,
    float* __restrict__ out)
{
    const int i = blockIdx.x;
    const int tid = threadIdx.x;
    const int lane = tid & 63, wave = tid >> 6;
    const int g = lane >> 4, c16 = lane & 15;

    __shared__ unsigned int smr[2 * WPB * 16 * RSTRIDE];
    __shared__ float sm_red[WPB][DD];
    __shared__ float sm_m[WPB], sm_l[WPB];

    // A fragments (loop-invariant)
    FragU aS[4][4], aR[4];
    #pragma unroll
    for (int b = 0; b < 4; ++b)
        #pragma unroll
        for (int c = 0; c < 4; ++c)
            aS[b][c].u4 = ((const uint4*)afragS)[(b * 4 + c) * 64 + lane];
    #pragma unroll
    for (int b = 0; b < 4; ++b) aR[b].u4 = ((const uint4*)afragR)[b * 64 + lane];

    // per-lane dout-set constants: dout = 16b + 4g + r
    float sb[16], nlwv[16], nlbv[16], wv16[16];
    #pragma unroll
    for (int b = 0; b < 4; ++b)
        #pragma unroll
        for (int r = 0; r < 4; ++r) {
            const int dout = 16 * b + g * 4 + r;
            sb[b * 4 + r]   = sbase[i * DD + dout];
            nlwv[b * 4 + r] = ng_lw[dout];
            nlbv[b * 4 + r] = ng_lb[dout];
            wv16[b * 4 + r] = war_w[dout];
        }

    const float m0 = mom[0], m1 = mom[1], m2 = mom[2], m3 = mom[3];
    const float M00 = mom[4], M11 = mom[5], M22 = mom[6], M33 = mom[7];
    const float M01 = mom[8], M02 = mom[9], M03 = mom[10];
    const float M12 = mom[11], M13 = mom[12], M23 = mom[13];

    const float warbase = warb[i];
    unsigned int* wrbase_a = smr + (wave * 16 + c16) * RSTRIDE;
    unsigned int* wrbase_b = wrbase_a + WPB * 16 * RSTRIDE;

    float acc[16];
    #pragma unroll
    for (int x = 0; x < 16; ++x) acc[x] = 0.f;
    float mrun = -INFINITY, lrun = 0.f;

    const f32x4 Z = {0.f, 0.f, 0.f, 0.f};

    // one j-tile front: loads -> angle -> GEMM1 -> LDS bounce -> GEMM2 -> LN stats, logit
    const auto tileS = [&](const int jj, unsigned int* const wrb,
                           f32x4* const S, float& p_o, bool& msk_o,
                           float& u2_o, float& inv2_o) {
        const float2 cc = ((const float2*)corr)[i * NN + jj];
        const float2 vv = ((const float2*)av)[jj];
        const int    nv = nei[i * NN + jj];
        const float  w3 = war3[jj];
        FragU bx2, bx3;
        bx2.u4 = *(const uint4*)(hf16 + jj * 32 + 4 * g);
        bx3.u4 = *(const uint4*)(hf16 + jj * 32 + 16 + 4 * g);

        const float cx = cc.x, cy = cc.y;
        const float judge = vv.x * vv.x + vv.y * vv.y;
        const float dotv = fmaf(vv.x, cx, vv.y * cy);
        const float cn = cx * cx + cy * cy;
        float angle = __fdividef(dotv, sqrtf(judge * cn) + 1e-10f);
        if (judge == 0.f) angle = -1.f;

        const float u = fmaf(cx, m0, fmaf(cy, m1, fmaf(angle, m2, m3)));
        float e2 = M33;
        e2 = fmaf(cx * cx, M00, e2);
        e2 = fmaf(cy * cy, M11, e2);
        e2 = fmaf(angle * angle, M22, e2);
        e2 = fmaf(2.f * cx, fmaf(cy, M01, fmaf(angle, M02, M03)), e2);
        e2 = fmaf(2.f * cy, fmaf(angle, M12, M13), e2);
        e2 = fmaf(2.f * angle, M23, e2);
        const float vare = (e2 - u * u) + 1e-5f;
        const float inv = rsqrtf(vare);
        const float sig = vare * inv;

        PkU s01, s23, s45;
        s01.p = __builtin_amdgcn_cvt_pkrtz(cx, cy);
        s23.p = __builtin_amdgcn_cvt_pkrtz(angle, 1.f);
        s45.p = __builtin_amdgcn_cvt_pkrtz(-u, sig);
        const unsigned l0 = pk2(cx - (float)s01.p[0], cy - (float)s01.p[1]);
        const unsigned l1 = pk2(angle - (float)s23.p[0], 0.f);
        const unsigned l2 = pk2((-u) - (float)s45.p[0], sig - (float)s45.p[1]);
        FragU b1;
        b1.u[0] = (g == 3) ? 0u : ((g == 1) ? l0 : s01.u);
        b1.u[1] = (g == 3) ? 0u : ((g == 1) ? l1 : s23.u);
        b1.u[2] = (g == 3) ? 0u : ((g == 1) ? l2 : s45.u);
        b1.u[3] = 0u;

        float wd = 0.f;
        #pragma unroll
        for (int b = 0; b < 4; ++b) {
            const f32x4 P = mfma16(aR[b], b1, Z);
            const float r0f = fmaxf(P[0], 0.f) * inv;
            const float r1f = fmaxf(P[1], 0.f) * inv;
            const float r2f = fmaxf(P[2], 0.f) * inv;
            const float r3f = fmaxf(P[3], 0.f) * inv;
            wd = fmaf(r0f, wv16[b * 4 + 0], wd);
            wd = fmaf(r1f, wv16[b * 4 + 1], wd);
            wd = fmaf(r2f, wv16[b * 4 + 2], wd);
            wd = fmaf(r3f, wv16[b * 4 + 3], wd);
            uint2 wv;
            wv.x = pk2(r0f, r1f);
            wv.y = pk2(r2f, r3f);
            *(uint2*)(wrb + 8 * b + 2 * g) = wv;
        }
        wd += __shfl_xor(wd, 16);
        wd += __shfl_xor(wd, 32);

        FragU bx0, bx1;
        {
            const uint2 lo0 = *(const uint2*)(wrb + 4 * g);
            const uint2 hi0 = *(const uint2*)(wrb + 4 * g + 2);
            bx0.u[0] = lo0.x; bx0.u[1] = lo0.y; bx0.u[2] = hi0.x; bx0.u[3] = hi0.y;
            const uint2 lo1 = *(const uint2*)(wrb + 16 + 4 * g);
            const uint2 hi1 = *(const uint2*)(wrb + 16 + 4 * g + 2);
            bx1.u[0] = lo1.x; bx1.u[1] = lo1.y; bx1.u[2] = hi1.x; bx1.u[3] = hi1.y;
        }

        #pragma unroll
        for (int b = 0; b < 4; ++b) {
            f32x4 cinit = {sb[b * 4 + 0], sb[b * 4 + 1], sb[b * 4 + 2], sb[b * 4 + 3]};
            cinit = mfma16(aS[b][0], bx0, cinit);
            cinit = mfma16(aS[b][1], bx1, cinit);
            cinit = mfma16(aS[b][2], bx2, cinit);
            cinit = mfma16(aS[b][3], bx3, cinit);
            S[b] = cinit;
        }

        float s1 = 0.f, s2 = 0.f;
        #pragma unroll
        for (int x = 0; x < 16; ++x) {
            const float sv = S[x >> 2][x & 3];
            s1 += sv; s2 = fmaf(sv, sv, s2);
        }
        s1 += __shfl_xor(s1, 16); s1 += __shfl_xor(s1, 32);
        s2 += __shfl_xor(s2, 16); s2 += __shfl_xor(s2, 32);
        const float u2 = s1 * (1.f / 64.f);
        const float var2 = fmaf(s2, 1.f / 64.f, -u2 * u2);
        u2_o = u2;
        inv2_o = rsqrtf(var2 + 1e-5f);

        float tt = wd + w3 + warbase;
        tt = fmaxf(tt, 0.f);
        const bool msk = nv > 0;
        msk_o = msk;
        p_o = (msk && tt > 0.f) ? tt : -10000.f;
    };

    #pragma unroll 1
    for (int t = 0; t < TPW2; ++t) {
        const int jj_a = 16 * (wave + WPB * t) + c16;
        const int jj_b = jj_a + NN / 2;

        f32x4 Sa[4], Sb[4];
        float p_a, p_b, u2a, u2b, inv2a, inv2b;
        bool  msk_a, msk_b;
        tileS(jj_a, wrbase_a, Sa, p_a, msk_a, u2a, inv2a);
        tileS(jj_b, wrbase_b, Sb, p_b, msk_b, u2b, inv2b);

        // merged online-softmax update over both tiles (32 j)
        float pm = fmaxf(p_a, p_b);
        pm = fmaxf(pm, __shfl_xor(pm, 1));
        pm = fmaxf(pm, __shfl_xor(pm, 2));
        pm = fmaxf(pm, __shfl_xor(pm, 4));
        pm = fmaxf(pm, __shfl_xor(pm, 8));
        const float mn = fmaxf(mrun, pm);
        const float alpha = __expf(mrun - mn);
        const float e_a = __expf(p_a - mn);
        const float e_b = __expf(p_b - mn);
        lrun = fmaf(lrun, alpha, e_a + e_b);
        mrun = mn;
        const float ea = msk_a ? e_a : 0.f;
        const float eb = msk_b ? e_b : 0.f;

        // gate + accumulate (both tiles in one rescale)
        #pragma unroll
        for (int b = 0; b < 4; ++b) {
            const f32x4 hva = *(const f32x4*)(hs + jj_a * DD + 16 * b + 4 * g);
            const f32x4 hvb = *(const f32x4*)(hs + jj_b * DD + 16 * b + 4 * g);
            #pragma unroll
            for (int r = 0; r < 4; ++r) {
                const float nga = fmaf((Sa[b][r] - u2a) * inv2a, nlwv[b * 4 + r],
                                       nlbv[b * 4 + r]);
                const float ngb = fmaf((Sb[b][r] - u2b) * inv2b, nlwv[b * 4 + r],
                                       nlbv[b * 4 + r]);
                const float ga = __fdividef(1.f, 1.f + __expf(-nga));
                const float gb = __fdividef(1.f, 1.f + __expf(-ngb));
                acc[b * 4 + r] = fmaf(acc[b * 4 + r], alpha,
                                      fmaf(ea * ga, hva[r], (eb * gb) * hvb[r]));
            }
        }
    }

    // reduce over the 16 j-classes (bits 0-3); g-duplicates are identical
    #pragma unroll
    for (int o = 1; o <= 8; o <<= 1) {
        lrun += __shfl_xor(lrun, o);
        #pragma unroll
        for (int x = 0; x < 16; ++x) acc[x] += __shfl_xor(acc[x], o);
    }
    if (c16 == 0) {
        #pragma unroll
        for (int b = 0; b < 4; ++b)
            #pragma unroll
            for (int r = 0; r < 4; ++r)
                sm_red[wave][16 * b + g * 4 + r] = acc[b * 4 + r];
        if (lane == 0) { sm_m[wave] = mrun; sm_l[wave] = lrun; }
    }
    __syncthreads();

    // fused k_out: out = h + relu(LN(Hsum@wt_w + wt_b))
    if (tid < DD) {
        float M = sm_m[0];
        #pragma unroll
        for (int w = 1; w < WPB; ++w) M = fmaxf(M, sm_m[w]);
        float L = 0.f, A = 0.f;
        #pragma unroll
        for (int w = 0; w < WPB; ++w) {
            const float f = __expf(sm_m[w] - M);
            L = fmaf(sm_l[w], f, L);
            A = fmaf(sm_red[w][tid], f, A);
        }
        const float Hv = A / L;
        float v = wt_b[tid];
        #pragma unroll 8
        for (int k = 0; k < DD; ++k)
            v = fmaf(lane_bcast(Hv, k), wt_w[k * DD + tid], v);
        float t1 = v, t2 = v * v;
        #pragma unroll
        for (int o = 32; o; o >>= 1) { t1 += __shfl_xor(t1, o); t2 += __shfl_xor(t2, o); }
        const float uo = t1 * (1.f / 64.f);
        const float varo = fmaf(t2, 1.f / 64.f, -uo * uo);
        const float invo = rsqrtf(varo + 1e-5f);
        const float ro = fmaf((v - uo) * invo, wt_lw[tid], wt_lb[tid]);
        out[i * DD + tid] = hs[i * DD + tid] + fmaxf(ro, 0.f);
    }
}

extern "C" void kernel_launch(void* const* d_in, const int* in_sizes, int n_in,
                              void* d_out, int out_size, void* d_ws, size_t ws_size,
                              hipStream_t stream) {
    const float* corr   = (const float*)d_in[0];
    const int*   nei    = (const int*)  d_in[1];
    // d_in[2] = nei_num : unused by the reference
    const float* hs     = (const float*)d_in[3];
    const float* av     = (const float*)d_in[4];
    const float* rel_w  = (const float*)d_in[5];
    const float* rel_b  = (const float*)d_in[6];
    const float* rel_lw = (const float*)d_in[7];
    const float* rel_lb = (const float*)d_in[8];
    const float* ng_w   = (const float*)d_in[9];
    const float* ng_b   = (const float*)d_in[10];
    const float* ng_lw  = (const float*)d_in[11];
    const float* ng_lb  = (const float*)d_in[12];
    const float* war_w  = (const float*)d_in[13];
    const float* war_b  = (const float*)d_in[14];
    const float* wt_w   = (const float*)d_in[15];
    const float* wt_b   = (const float*)d_in[16];
    const float* wt_lw  = (const float*)d_in[17];
    const float* wt_lb  = (const float*)d_in[18];
    float* out = (float*)d_out;

    float* ws    = (float*)d_ws;
    float* sbase = ws;                                  // N*D
    float* warb  = sbase + NN * DD;                     // N
    float* war3  = warb + NN;                           // N
    float* mom   = war3 + NN;                           // 14 (+pad to 16)
    unsigned int* hf16   = (unsigned int*)(mom + 16);   // N*32
    unsigned int* afragS = hf16 + NN * 32;              // 16*64*4
    unsigned int* afragR = afragS + 16 * 64 * 4;        // 4*64*4

    k_prepack<<<PREBLKS + NN / 4, 256, 0, stream>>>(
        hs, ng_w, ng_b, war_w, war_b, rel_w, rel_b, rel_lw, rel_lb,
        sbase, warb, war3, hf16, afragS, afragR, mom);
    k_main<<<NN, 64 * WPB, 0, stream>>>(
        corr, nei, hs, av, ng_lw, ng_lb, war_w, sbase, warb, war3,
        afragS, afragR, hf16, mom, wt_w, wt_b, wt_lw, wt_lb, out);
}

// Round 11
// 146.723 us; speedup vs baseline: 1.1885x; 1.1885x over previous
//
#include <hip/hip_runtime.h>
#include <math.h>

#define NN 768
#define DD 64
#define WPB 4                        // waves per block in k_main
#define TPW (NN / 16 / WPB)          // tiles (of 16 j) per wave = 12
#define RSTRIDE 34                   // LDS r-bounce row stride in dwords (pad 2)
#define PREBLKS 18                   // k_prepack: frag/pack blocks before row blocks

typedef _Float16 half8 __attribute__((ext_vector_type(8)));
typedef float    f32x4 __attribute__((ext_vector_type(4)));
typedef __fp16   p2f   __attribute__((ext_vector_type(2)));

union FragU { uint4 u4; unsigned int u[4]; half8 h; };
union PkU   { unsigned int u; p2f p; };

__device__ __forceinline__ unsigned int pk2(float a, float b) {
    PkU t; t.p = __builtin_amdgcn_cvt_pkrtz(a, b); return t.u;
}
__device__ __forceinline__ float lane_bcast(float v, int src) {
    return __int_as_float(__builtin_amdgcn_readlane(__float_as_int(v), src));
}
__device__ __forceinline__ f32x4 mfma16(FragU a, FragU b, f32x4 c) {
    return __builtin_amdgcn_mfma_f32_16x16x32_f16(a.h, b.h, c, 0, 0, 0);
}

// ---------- Kernel 0: pack fragments / hf16 / moments (blk<18) + per-row pre (blk>=18)
__global__ __launch_bounds__(256) void k_prepack(
    const float* __restrict__ hs, const float* __restrict__ ng_w,
    const float* __restrict__ ng_b, const float* __restrict__ war_w,
    const float* __restrict__ war_b,
    const float* __restrict__ rel_w, const float* __restrict__ rel_b,
    const float* __restrict__ rel_lw, const float* __restrict__ rel_lb,
    float* __restrict__ sbase, float* __restrict__ warb, float* __restrict__ war3,
    unsigned int* __restrict__ hf16,
    unsigned int* __restrict__ afragS, unsigned int* __restrict__ afragR,
    float* __restrict__ mom)
{
    const int t = threadIdx.x, blk = blockIdx.x;
    const int lane = t & 63, q = t >> 6, g = lane >> 4, c16 = lane & 15;

    if (blk >= PREBLKS) {
        // per-row: sbase = h@W2 + ng_b ; warb = h@war[64:128] + war_b ; war3 = h@war[128:192]
        const int row = (blk - PREBLKS) * 4 + q;
        const float hv = hs[row * DD + lane];
        float a2 = ng_b[lane];
        #pragma unroll 8
        for (int k = 0; k < DD; ++k)
            a2 = fmaf(lane_bcast(hv, k), ng_w[(DD + k) * DD + lane], a2);
        sbase[row * DD + lane] = a2;
        float t2 = hv * war_w[DD + lane];
        float t3 = hv * war_w[2 * DD + lane];
        #pragma unroll
        for (int o = 32; o; o >>= 1) { t2 += __shfl_xor(t2, o); t3 += __shfl_xor(t3, o); }
        if (lane == 0) { warb[row] = t2 + war_b[0]; war3[row] = t3; }
        return;
    }

    // hf16 pack across blocks 0..17
    for (int idx = blk * 256 + t; idx < NN * 32; idx += PREBLKS * 256) {
        const int row = idx >> 5, c = idx & 31;
        hf16[idx] = pk2(hs[row * DD + 2 * c], hs[row * DD + 2 * c + 1]);
    }

    if (blk < 16) {
        // GEMM2 S A-fragments: A[m=dout][k], frag id = b*4+c
        const int b = blk >> 2, c = blk & 3;
        const int dout = 16 * b + c16;
        const int k0 = 32 * c + g * 8 + 2 * q;
        const int r0 = (k0 < 64) ? k0 : (k0 + 64);   // W1 rows 0..63 ; W3 rows 128..191
        afragS[(blk * 64 + lane) * 4 + q] =
            pk2(ng_w[r0 * DD + dout], ng_w[(r0 + 1) * DD + dout]);
    } else if (blk == 16) {
        // GEMM1 A-fragments, split-precision:
        //   k0..5: wh (pairs xh) ; k8..13: wh (pairs xl) ; k16..21: wl (pairs xh)
        const int b = q;                      // m-block
        const int d = 16 * b + c16;
        const float rlwd = rel_lw[d], rlbd = rel_lb[d];
        const float c0 = rel_w[d] * rlwd;
        const float c1 = rel_w[DD + d] * rlwd;
        const float c2 = rel_w[2 * DD + d] * rlwd;
        const float c3 = rel_b[d] * rlwd;
        PkU h01, h23, h45;
        h01.p = __builtin_amdgcn_cvt_pkrtz(c0, c1);
        h23.p = __builtin_amdgcn_cvt_pkrtz(c2, c3);
        h45.p = __builtin_amdgcn_cvt_pkrtz(rlwd, rlbd);
        const unsigned l01 = pk2(c0 - (float)h01.p[0], c1 - (float)h01.p[1]);
        const unsigned l23 = pk2(c2 - (float)h23.p[0], c3 - (float)h23.p[1]);
        const unsigned l45 = pk2(rlwd - (float)h45.p[0], rlbd - (float)h45.p[1]);
        const unsigned int base = (b * 64 + lane) * 4;
        unsigned v0, v1, v2;
        if (g == 0 || g == 1)      { v0 = h01.u; v1 = h23.u; v2 = h45.u; }
        else if (g == 2)           { v0 = l01;   v1 = l23;   v2 = l45;   }
        else                       { v0 = 0u;    v1 = 0u;    v2 = 0u;    }
        afragR[base + 0] = v0;
        afragR[base + 1] = v1;
        afragR[base + 2] = v2;
        afragR[base + 3] = 0u;
    } else { // blk == 17: rel-LN moment matrix
        if (t < 64) {
            const float x0 = rel_w[t], x1 = rel_w[DD + t], x2 = rel_w[2 * DD + t];
            const float x3 = rel_b[t];
            float v[14] = {x0, x1, x2, x3,
                           x0 * x0, x1 * x1, x2 * x2, x3 * x3,
                           x0 * x1, x0 * x2, x0 * x3, x1 * x2, x1 * x3, x2 * x3};
            #pragma unroll
            for (int qq = 0; qq < 14; ++qq) {
                float s = v[qq];
                #pragma unroll
                for (int o = 32; o; o >>= 1) s += __shfl_xor(s, o);
                if (t == 0) mom[qq] = s * (1.f / 64.f);
            }
        }
    }
}

// ---------- Kernel 1: per-row i, 16-j tiles via MFMA, online softmax,
//            front-chain prefetch, fused final MLP + residual ----------------
__global__ __launch_bounds__(64 * WPB) void k_main(
    const float* __restrict__ corr, const int* __restrict__ nei,
    const float* __restrict__ hs, const float* __restrict__ av,
    const float* __restrict__ ng_lw, const float* __restrict__ ng_lb,
    const float* __restrict__ war_w,
    const float* __restrict__ sbase, const float* __restrict__ warb,
    const float* __restrict__ war3,
    const unsigned int* __restrict__ afragS, const unsigned int* __restrict__ afragR,
    const unsigned int* __restrict__ hf16, const float* __restrict__ mom,
    const float* __restrict__ wt_w, const float* __restrict__ wt_b,
    const float* __restrict__ wt_lw, const float* __restrict__ wt_lb,
    float* __restrict__ out)
{
    const int i = blockIdx.x;
    const int tid = threadIdx.x;
    const int lane = tid & 63, wave = tid >> 6;
    const int g = lane >> 4, c16 = lane & 15;

    __shared__ unsigned int smr[WPB * 16 * RSTRIDE];
    __shared__ float sm_red[WPB][DD];
    __shared__ float sm_m[WPB], sm_l[WPB];

    // A fragments (loop-invariant)
    FragU aS[4][4], aR[4];
    #pragma unroll
    for (int b = 0; b < 4; ++b)
        #pragma unroll
        for (int c = 0; c < 4; ++c)
            aS[b][c].u4 = ((const uint4*)afragS)[(b * 4 + c) * 64 + lane];
    #pragma unroll
    for (int b = 0; b < 4; ++b) aR[b].u4 = ((const uint4*)afragR)[b * 64 + lane];

    // per-lane dout-set constants: dout = 16b + 4g + r
    float sb[16], nlwv[16], nlbv[16], wv16[16];
    #pragma unroll
    for (int b = 0; b < 4; ++b)
        #pragma unroll
        for (int r = 0; r < 4; ++r) {
            const int dout = 16 * b + g * 4 + r;
            sb[b * 4 + r]   = sbase[i * DD + dout];
            nlwv[b * 4 + r] = ng_lw[dout];
            nlbv[b * 4 + r] = ng_lb[dout];
            wv16[b * 4 + r] = war_w[dout];
        }

    const float m0 = mom[0], m1 = mom[1], m2 = mom[2], m3 = mom[3];
    const float M00 = mom[4], M11 = mom[5], M22 = mom[6], M33 = mom[7];
    const float M01 = mom[8], M02 = mom[9], M03 = mom[10];
    const float M12 = mom[11], M13 = mom[12], M23 = mom[13];

    const float warbase = warb[i];
    unsigned int* wrbase = smr + (wave * 16 + c16) * RSTRIDE;

    float acc[16];
    #pragma unroll
    for (int x = 0; x < 16; ++x) acc[x] = 0.f;
    float mrun = -INFINITY, lrun = 0.f;

    // prefetch tile 0's front-of-chain loads
    int jj = 16 * wave + c16;
    float2 cc = ((const float2*)corr)[i * NN + jj];
    float2 vv = ((const float2*)av)[jj];
    int    nv = nei[i * NN + jj];
    float  w3 = war3[jj];
    FragU bx2, bx3;
    bx2.u4 = *(const uint4*)(hf16 + jj * 32 + 4 * g);
    bx3.u4 = *(const uint4*)(hf16 + jj * 32 + 16 + 4 * g);

    #pragma unroll 1
    for (int t = 0; t < TPW; ++t) {
        // current tile's late loads issued up-front (consumed in epilogue)
        const f32x4 hv0 = *(const f32x4*)(hs + jj * DD +  0 + 4 * g);
        const f32x4 hv1 = *(const f32x4*)(hs + jj * DD + 16 + 4 * g);
        const f32x4 hv2 = *(const f32x4*)(hs + jj * DD + 32 + 4 * g);
        const f32x4 hv3 = *(const f32x4*)(hs + jj * DD + 48 + 4 * g);

        // next tile's front-of-chain prefetch (in flight during this tile's compute)
        const int tn  = (t + 1 < TPW) ? (t + 1) : t;
        const int jjn = 16 * (wave + WPB * tn) + c16;
        const float2 cc_n = ((const float2*)corr)[i * NN + jjn];
        const float2 vv_n = ((const float2*)av)[jjn];
        const int    nv_n = nei[i * NN + jjn];
        const float  w3_n = war3[jjn];
        FragU bx2_n, bx3_n;
        bx2_n.u4 = *(const uint4*)(hf16 + jjn * 32 + 4 * g);
        bx3_n.u4 = *(const uint4*)(hf16 + jjn * 32 + 16 + 4 * g);

        const float cx = cc.x, cy = cc.y;
        const float judge = vv.x * vv.x + vv.y * vv.y;
        const float dotv = fmaf(vv.x, cx, vv.y * cy);
        const float cn = cx * cx + cy * cy;
        float angle = __fdividef(dotv, sqrtf(judge * cn) + 1e-10f);
        if (judge == 0.f) angle = -1.f;

        // analytic rel-LN stats (quadratic form)
        const float u = fmaf(cx, m0, fmaf(cy, m1, fmaf(angle, m2, m3)));
        float e2 = M33;
        e2 = fmaf(cx * cx, M00, e2);
        e2 = fmaf(cy * cy, M11, e2);
        e2 = fmaf(angle * angle, M22, e2);
        e2 = fmaf(2.f * cx, fmaf(cy, M01, fmaf(angle, M02, M03)), e2);
        e2 = fmaf(2.f * cy, fmaf(angle, M12, M13), e2);
        e2 = fmaf(2.f * angle, M23, e2);
        const float vare = (e2 - u * u) + 1e-5f;
        const float inv = rsqrtf(vare);
        const float sig = vare * inv;               // sqrt(vare)

        // GEMM1 B operand, split-precision: x = (cx, cy, angle, 1, -u, sig)
        PkU s01, s23, s45;
        s01.p = __builtin_amdgcn_cvt_pkrtz(cx, cy);
        s23.p = __builtin_amdgcn_cvt_pkrtz(angle, 1.f);
        s45.p = __builtin_amdgcn_cvt_pkrtz(-u, sig);
        const unsigned l0 = pk2(cx - (float)s01.p[0], cy - (float)s01.p[1]);
        const unsigned l1 = pk2(angle - (float)s23.p[0], 0.f);
        const unsigned l2 = pk2((-u) - (float)s45.p[0], sig - (float)s45.p[1]);
        FragU b1;
        b1.u[0] = (g == 3) ? 0u : ((g == 1) ? l0 : s01.u);
        b1.u[1] = (g == 3) ? 0u : ((g == 1) ? l1 : s23.u);
        b1.u[2] = (g == 3) ? 0u : ((g == 1) ? l2 : s45.u);
        b1.u[3] = 0u;

        const f32x4 Z = {0.f, 0.f, 0.f, 0.f};
        // GEMM1 -> r (f32-accurate); war dot in f32 inline; f16 pack to LDS
        float wd = 0.f;
        #pragma unroll
        for (int b = 0; b < 4; ++b) {
            const f32x4 P = mfma16(aR[b], b1, Z);
            const float r0f = fmaxf(P[0], 0.f) * inv;
            const float r1f = fmaxf(P[1], 0.f) * inv;
            const float r2f = fmaxf(P[2], 0.f) * inv;
            const float r3f = fmaxf(P[3], 0.f) * inv;
            wd = fmaf(r0f, wv16[b * 4 + 0], wd);
            wd = fmaf(r1f, wv16[b * 4 + 1], wd);
            wd = fmaf(r2f, wv16[b * 4 + 2], wd);
            wd = fmaf(r3f, wv16[b * 4 + 3], wd);
            uint2 wv;
            wv.x = pk2(r0f, r1f);
            wv.y = pk2(r2f, r3f);
            *(uint2*)(wrbase + 8 * b + 2 * g) = wv;   // d2 = 8b+2g, +1
        }
        wd += __shfl_xor(wd, 16);
        wd += __shfl_xor(wd, 32);     // full r@war[0:64] for this lane's jj, f32

        // GEMM2 B operands: chunks 0,1 = r (LDS), chunks 2,3 = h_j (prefetched)
        FragU bx0, bx1;
        {
            const uint2 lo0 = *(const uint2*)(wrbase + 4 * g);
            const uint2 hi0 = *(const uint2*)(wrbase + 4 * g + 2);
            bx0.u[0] = lo0.x; bx0.u[1] = lo0.y; bx0.u[2] = hi0.x; bx0.u[3] = hi0.y;
            const uint2 lo1 = *(const uint2*)(wrbase + 16 + 4 * g);
            const uint2 hi1 = *(const uint2*)(wrbase + 16 + 4 * g + 2);
            bx1.u[0] = lo1.x; bx1.u[1] = lo1.y; bx1.u[2] = hi1.x; bx1.u[3] = hi1.y;
        }

        // GEMM2: S[dout][j] with C-init = sbase
        f32x4 S[4];
        #pragma unroll
        for (int b = 0; b < 4; ++b) {
            f32x4 cinit = {sb[b * 4 + 0], sb[b * 4 + 1], sb[b * 4 + 2], sb[b * 4 + 3]};
            cinit = mfma16(aS[b][0], bx0, cinit);
            cinit = mfma16(aS[b][1], bx1, cinit);
            cinit = mfma16(aS[b][2], bx2, cinit);
            cinit = mfma16(aS[b][3], bx3, cinit);
            S[b] = cinit;
        }

        // LayerNorm stats over dout (in-lane 16 + xor16/32)
        float s1 = 0.f, s2 = 0.f;
        #pragma unroll
        for (int x = 0; x < 16; ++x) {
            const float sv = S[x >> 2][x & 3];
            s1 += sv; s2 = fmaf(sv, sv, s2);
        }
        s1 += __shfl_xor(s1, 16); s1 += __shfl_xor(s1, 32);
        s2 += __shfl_xor(s2, 16); s2 += __shfl_xor(s2, 32);
        const float u2 = s1 * (1.f / 64.f);
        const float var2 = fmaf(s2, 1.f / 64.f, -u2 * u2);
        const float inv2 = rsqrtf(var2 + 1e-5f);

        // attention logit: full f32 (the -10000 cliff demands it)
        float tt = wd + w3 + warbase;
        tt = fmaxf(tt, 0.f);
        const bool msk = nv > 0;
        const float p = (msk && tt > 0.f) ? tt : -10000.f;

        // tile max over 16 j -> wave-uniform online-softmax update
        float pm = p;
        pm = fmaxf(pm, __shfl_xor(pm, 1));
        pm = fmaxf(pm, __shfl_xor(pm, 2));
        pm = fmaxf(pm, __shfl_xor(pm, 4));
        pm = fmaxf(pm, __shfl_xor(pm, 8));
        const float mn = fmaxf(mrun, pm);
        const float alpha = __expf(mrun - mn);
        const float e = __expf(p - mn);
        const float eacc = msk ? e : 0.f;
        lrun = fmaf(lrun, alpha, e);
        mrun = mn;

        // gate + accumulate
        #pragma unroll
        for (int b = 0; b < 4; ++b) {
            const f32x4 hvb = (b == 0) ? hv0 : (b == 1) ? hv1 : (b == 2) ? hv2 : hv3;
            #pragma unroll
            for (int r = 0; r < 4; ++r) {
                const float ngv = fmaf((S[b][r] - u2) * inv2, nlwv[b * 4 + r],
                                       nlbv[b * 4 + r]);
                const float gate = __fdividef(1.f, 1.f + __expf(-ngv));
                acc[b * 4 + r] = fmaf(acc[b * 4 + r], alpha, eacc * gate * hvb[r]);
            }
        }

        // rotate prefetched state
        jj = jjn; cc = cc_n; vv = vv_n; nv = nv_n; w3 = w3_n;
        bx2 = bx2_n; bx3 = bx3_n;
    }

    // reduce over the 16 j-classes (bits 0-3); g-duplicates are identical
    #pragma unroll
    for (int o = 1; o <= 8; o <<= 1) {
        lrun += __shfl_xor(lrun, o);
        #pragma unroll
        for (int x = 0; x < 16; ++x) acc[x] += __shfl_xor(acc[x], o);
    }
    if (c16 == 0) {
        #pragma unroll
        for (int b = 0; b < 4; ++b)
            #pragma unroll
            for (int r = 0; r < 4; ++r)
                sm_red[wave][16 * b + g * 4 + r] = acc[b * 4 + r];
        if (lane == 0) { sm_m[wave] = mrun; sm_l[wave] = lrun; }
    }
    __syncthreads();

    // fused k_out: out = h + relu(LN(Hsum@wt_w + wt_b))
    if (tid < DD) {
        float M = sm_m[0];
        #pragma unroll
        for (int w = 1; w < WPB; ++w) M = fmaxf(M, sm_m[w]);
        float L = 0.f, A = 0.f;
        #pragma unroll
        for (int w = 0; w < WPB; ++w) {
            const float f = __expf(sm_m[w] - M);
            L = fmaf(sm_l[w], f, L);
            A = fmaf(sm_red[w][tid], f, A);
        }
        const float Hv = A / L;
        float v = wt_b[tid];
        #pragma unroll 8
        for (int k = 0; k < DD; ++k)
            v = fmaf(lane_bcast(Hv, k), wt_w[k * DD + tid], v);
        float t1 = v, t2 = v * v;
        #pragma unroll
        for (int o = 32; o; o >>= 1) { t1 += __shfl_xor(t1, o); t2 += __shfl_xor(t2, o); }
        const float uo = t1 * (1.f / 64.f);
        const float varo = fmaf(t2, 1.f / 64.f, -uo * uo);
        const float invo = rsqrtf(varo + 1e-5f);
        const float ro = fmaf((v - uo) * invo, wt_lw[tid], wt_lb[tid]);
        out[i * DD + tid] = hs[i * DD + tid] + fmaxf(ro, 0.f);
    }
}

extern "C" void kernel_launch(void* const* d_in, const int* in_sizes, int n_in,
                              void* d_out, int out_size, void* d_ws, size_t ws_size,
                              hipStream_t stream) {
    const float* corr   = (const float*)d_in[0];
    const int*   nei    = (const int*)  d_in[1];
    // d_in[2] = nei_num : unused by the reference
    const float* hs     = (const float*)d_in[3];
    const float* av     = (const float*)d_in[4];
    const float* rel_w  = (const float*)d_in[5];
    const float* rel_b  = (const float*)d_in[6];
    const float* rel_lw = (const float*)d_in[7];
    const float* rel_lb = (const float*)d_in[8];
    const float* ng_w   = (const float*)d_in[9];
    const float* ng_b   = (const float*)d_in[10];
    const float* ng_lw  = (const float*)d_in[11];
    const float* ng_lb  = (const float*)d_in[12];
    const float* war_w  = (const float*)d_in[13];
    const float* war_b  = (const float*)d_in[14];
    const float* wt_w   = (const float*)d_in[15];
    const float* wt_b   = (const float*)d_in[16];
    const float* wt_lw  = (const float*)d_in[17];
    const float* wt_lb  = (const float*)d_in[18];
    float* out = (float*)d_out;

    float* ws    = (float*)d_ws;
    float* sbase = ws;                                  // N*D
    float* warb  = sbase + NN * DD;                     // N
    float* war3  = warb + NN;                           // N
    float* mom   = war3 + NN;                           // 14 (+pad to 16)
    unsigned int* hf16   = (unsigned int*)(mom + 16);   // N*32
    unsigned int* afragS = hf16 + NN * 32;              // 16*64*4
    unsigned int* afragR = afragS + 16 * 64 * 4;        // 4*64*4

    k_prepack<<<PREBLKS + NN / 4, 256, 0, stream>>>(
        hs, ng_w, ng_b, war_w, war_b, rel_w, rel_b, rel_lw, rel_lb,
        sbase, warb, war3, hf16, afragS, afragR, mom);
    k_main<<<NN, 64 * WPB, 0, stream>>>(
        corr, nei, hs, av, ng_lw, ng_lb, war_w, sbase, warb, war3,
        afragS, afragR, hf16, mom, wt_w, wt_b, wt_lw, wt_lb, out);
}